// Round 2
// baseline (855.407 us; speedup 1.0000x reference)
//
#include <hip/hip_runtime.h>

#define NN 50000
#define NE 300000
#define EDGE_TILES 4688   // ceil(NE/64)

typedef _Float16 f16;
typedef _Float16 f16x4 __attribute__((ext_vector_type(4)));
typedef float f32x4 __attribute__((ext_vector_type(4)));

#define A_STRIDE 136   // 128 + 8 pad, f16 elements
#define A2_STRIDE 72   // 64 + 8 pad

struct Job { const float* x; const int* idx; const float* attr;
             const float* W; const float* b; float* h; };
struct Jobs6 { Job j[6]; };

__device__ __forceinline__ f16x4 cvt4(float4 v) {
    f16x4 r; r.x = (f16)v.x; r.y = (f16)v.y; r.z = (f16)v.z; r.w = (f16)v.w;
    return r;
}

// ---------------- init: h = 2*x for all 3 levels ----------------
__global__ void init_kernel(const float* __restrict__ x0, const float* __restrict__ x1,
                            const float* __restrict__ x2, float* __restrict__ hbase) {
    const float* xs[3] = {x0, x1, x2};
    const int lvl = blockIdx.y;
    const int i   = blockIdx.x * 256 + threadIdx.x;   // 3125*256 == NN*16 exactly
    float4 v = ((const float4*)xs[lvl])[i];
    ((float4*)(hbase + (size_t)lvl * NN * 64))[i] =
        make_float4(2.f * v.x, 2.f * v.y, 2.f * v.z, 2.f * v.w);
}

// ---------------- edge MLP + scatter-add: one 64-edge tile per block ----------------
__global__ void edge_kernel(Jobs6 jobs) {
    __shared__ f16 As[64 * A_STRIDE];
    __shared__ int tgt_s[64];
    __shared__ int src_s[64];

    const Job J = jobs.j[blockIdx.y];

    const int t    = threadIdx.x;
    const int lane = t & 63;
    const int wid  = t >> 6;
    const int lr   = lane & 15;
    const int lg   = lane >> 4;

    // Preload W fragments into registers (issued early, overlaps staging)
    f16x4 wf[8][4];
#pragma unroll
    for (int k0 = 0; k0 < 8; ++k0) {
        const int kb = k0 * 16 + 4 * lg;
#pragma unroll
        for (int n = 0; n < 4; ++n) {
            const int c = n * 16 + lr;
            f16x4 w;
            w.x = (f16)J.W[(kb + 0) * 64 + c];
            w.y = (f16)J.W[(kb + 1) * 64 + c];
            w.z = (f16)J.W[(kb + 2) * 64 + c];
            w.w = (f16)J.W[(kb + 3) * 64 + c];
            wf[k0][n] = w;
        }
    }
    float bf[4];
#pragma unroll
    for (int n = 0; n < 4; ++n) bf[n] = J.b[n * 16 + lr];

    const int e0 = blockIdx.x << 6;
    if (t < 64) {
        int e = e0 + t;
        tgt_s[t] = (e < NE) ? J.idx[e] : -1;
        src_s[t] = (e < NE) ? J.idx[NE + e] : 0;
    }
    __syncthreads();

    // stage A = [x[src] | attr] as f16 into LDS
    {
        const float4* x4 = (const float4*)J.x;
        const float4* a4 = (const float4*)J.attr;
        const int rb = t >> 4;        // row base 0..15
        const int cq = t & 15;        // float4 column
#pragma unroll
        for (int i = 0; i < 4; ++i) {
            const int rr = rb + i * 16;
            const int s  = src_s[rr];
            float4 vx = x4[(size_t)s * 16 + cq];
            *(f16x4*)&As[rr * A_STRIDE + cq * 4] = cvt4(vx);
            const int e = e0 + rr;
            float4 va = (e < NE) ? a4[(size_t)e * 16 + cq]
                                 : make_float4(0.f, 0.f, 0.f, 0.f);
            *(f16x4*)&As[rr * A_STRIDE + 64 + cq * 4] = cvt4(va);
        }
    }
    __syncthreads();

    // MFMA: wave wid owns rows [wid*16, wid*16+16)
    const int r0 = wid << 4;
    f32x4 acc[4];
#pragma unroll
    for (int n = 0; n < 4; ++n) acc[n] = (f32x4){0.f, 0.f, 0.f, 0.f};
#pragma unroll
    for (int k0 = 0; k0 < 8; ++k0) {
        f16x4 a = *(const f16x4*)&As[(r0 + lr) * A_STRIDE + k0 * 16 + 4 * lg];
#pragma unroll
        for (int n = 0; n < 4; ++n)
            acc[n] = __builtin_amdgcn_mfma_f32_16x16x16f16(a, wf[k0][n], acc[n], 0, 0, 0);
    }

    // bias + relu + fire-and-forget atomic scatter (no trailing barrier)
#pragma unroll
    for (int n = 0; n < 4; ++n) {
#pragma unroll
        for (int j = 0; j < 4; ++j) {
            const int r  = 4 * lg + j;
            const int tg = tgt_s[r0 + r];
            float v = acc[n][j] + bf[n];
            v = v > 0.f ? v : 0.f;
            if (tg >= 0) unsafeAtomicAdd(&J.h[(size_t)tg * 64 + n * 16 + lr], v);
        }
    }
}

// ---------------- node MLP (in place, all 3 levels) ----------------
__global__ void node_kernel(float* __restrict__ hbase,
                            const float* __restrict__ W1, const float* __restrict__ b1,
                            const float* __restrict__ W2, const float* __restrict__ b2) {
    __shared__ f16 As[64 * A2_STRIDE];

    float* io = hbase + (size_t)blockIdx.y * NN * 64;

    const int t    = threadIdx.x;
    const int lane = t & 63;
    const int wid  = t >> 6;
    const int lr   = lane & 15;
    const int lg   = lane >> 4;

    f16x4 w1f[4][4], w2f[4][4];
#pragma unroll
    for (int k0 = 0; k0 < 4; ++k0) {
        const int kb = k0 * 16 + 4 * lg;
#pragma unroll
        for (int n = 0; n < 4; ++n) {
            const int c = n * 16 + lr;
            f16x4 w;
            w.x = (f16)W1[(kb + 0) * 64 + c];
            w.y = (f16)W1[(kb + 1) * 64 + c];
            w.z = (f16)W1[(kb + 2) * 64 + c];
            w.w = (f16)W1[(kb + 3) * 64 + c];
            w1f[k0][n] = w;
            w.x = (f16)W2[(kb + 0) * 64 + c];
            w.y = (f16)W2[(kb + 1) * 64 + c];
            w.z = (f16)W2[(kb + 2) * 64 + c];
            w.w = (f16)W2[(kb + 3) * 64 + c];
            w2f[k0][n] = w;
        }
    }
    float b1f[4], b2f[4];
#pragma unroll
    for (int n = 0; n < 4; ++n) {
        b1f[n] = b1[n * 16 + lr];
        b2f[n] = b2[n * 16 + lr];
    }

    const float4* io4 = (const float4*)io;
    const int n0 = blockIdx.x << 6;
    {
        const int rb = t >> 4;
        const int cq = t & 15;
#pragma unroll
        for (int i = 0; i < 4; ++i) {
            const int rr   = rb + i * 16;
            const int node = n0 + rr;
            float4 v = (node < NN) ? io4[(size_t)node * 16 + cq]
                                   : make_float4(0.f, 0.f, 0.f, 0.f);
            *(f16x4*)&As[rr * A2_STRIDE + cq * 4] = cvt4(v);
        }
    }
    __syncthreads();

    const int r0 = wid << 4;
    f32x4 acc[4];
#pragma unroll
    for (int n = 0; n < 4; ++n) acc[n] = (f32x4){0.f, 0.f, 0.f, 0.f};
#pragma unroll
    for (int k0 = 0; k0 < 4; ++k0) {
        f16x4 a = *(const f16x4*)&As[(r0 + lr) * A2_STRIDE + k0 * 16 + 4 * lg];
#pragma unroll
        for (int n = 0; n < 4; ++n)
            acc[n] = __builtin_amdgcn_mfma_f32_16x16x16f16(a, w1f[k0][n], acc[n], 0, 0, 0);
    }
    // y1 = relu(acc + b1) written back transposed to A-layout; same-wave rows only
#pragma unroll
    for (int n = 0; n < 4; ++n) {
#pragma unroll
        for (int j = 0; j < 4; ++j) {
            const int r = 4 * lg + j;
            float v = acc[n][j] + b1f[n];
            v = v > 0.f ? v : 0.f;
            As[(r0 + r) * A2_STRIDE + n * 16 + lr] = (f16)v;
        }
    }
    f32x4 acc2[4];
#pragma unroll
    for (int n = 0; n < 4; ++n) acc2[n] = (f32x4){0.f, 0.f, 0.f, 0.f};
#pragma unroll
    for (int k0 = 0; k0 < 4; ++k0) {
        f16x4 a = *(const f16x4*)&As[(r0 + lr) * A2_STRIDE + k0 * 16 + 4 * lg];
#pragma unroll
        for (int n = 0; n < 4; ++n)
            acc2[n] = __builtin_amdgcn_mfma_f32_16x16x16f16(a, w2f[k0][n], acc2[n], 0, 0, 0);
    }
#pragma unroll
    for (int n = 0; n < 4; ++n) {
#pragma unroll
        for (int j = 0; j < 4; ++j) {
            const int r    = 4 * lg + j;
            const int node = n0 + r0 + r;
            float v = acc2[n][j] + b2f[n];
            v = v > 0.f ? v : 0.f;
            if (node < NN) io[(size_t)node * 64 + n * 16 + lr] = v;
        }
    }
}

extern "C" void kernel_launch(void* const* d_in, const int* in_sizes, int n_in,
                              void* d_out, int out_size, void* d_ws, size_t ws_size,
                              hipStream_t stream) {
    (void)in_sizes; (void)n_in; (void)d_ws; (void)ws_size; (void)out_size;

    const float* W_up   = (const float*)d_in[15];
    const float* b_up   = (const float*)d_in[16];
    const float* W_down = (const float*)d_in[17];
    const float* b_down = (const float*)d_in[18];
    const float* W1     = (const float*)d_in[19];
    const float* b1     = (const float*)d_in[20];
    const float* W2     = (const float*)d_in[21];
    const float* b2     = (const float*)d_in[22];

    float* hbase = (float*)d_out;

    Jobs6 jobs;
    for (int d = 0; d < 3; ++d) {
        const float* x  = (const float*)d_in[5 * d + 0];
        const int*   ui = (const int*)  d_in[5 * d + 1];
        const int*   di = (const int*)  d_in[5 * d + 2];
        const float* ua = (const float*)d_in[5 * d + 3];
        const float* da = (const float*)d_in[5 * d + 4];
        float* h = hbase + (size_t)d * NN * 64;
        jobs.j[2 * d + 0] = {x, ui, ua, W_up,   b_up,   h};
        jobs.j[2 * d + 1] = {x, di, da, W_down, b_down, h};
    }

    init_kernel<<<dim3(3125, 3), 256, 0, stream>>>(
        (const float*)d_in[0], (const float*)d_in[5], (const float*)d_in[10], hbase);
    edge_kernel<<<dim3(EDGE_TILES, 6), 256, 0, stream>>>(jobs);
    node_kernel<<<dim3(782, 3), 256, 0, stream>>>(hbase, W1, b1, W2, b2);
}

// Round 3
// 468.790 us; speedup vs baseline: 1.8247x; 1.8247x over previous
//
#include <hip/hip_runtime.h>
#include <hip/hip_fp16.h>

#define NN 50000
#define NE 300000
#define ETILES (NE / 16)        // 18750
#define NTILES (NN / 16)        // 3125

typedef _Float16 f16;
typedef _Float16 f16x4 __attribute__((ext_vector_type(4)));
typedef float f32x4 __attribute__((ext_vector_type(4)));

__device__ __forceinline__ f16x4 cvt4(float4 v) {
    f16x4 r; r.x = (f16)v.x; r.y = (f16)v.y; r.z = (f16)v.z; r.w = (f16)v.w;
    return r;
}

// ---------------- init: h = 2*x for all 3 levels ----------------
template<bool HALF>
__global__ void init_kernel(const float* __restrict__ x0, const float* __restrict__ x1,
                            const float* __restrict__ x2, void* __restrict__ hbase) {
    const size_t i = (size_t)blockIdx.x * 256 + threadIdx.x;   // float4 index; 9375*256 == 3*NN*16
    const int lvl = (int)(i / (NN * 16));
    const size_t li = i - (size_t)lvl * (NN * 16);
    const float* xs = (lvl == 0) ? x0 : (lvl == 1) ? x1 : x2;
    float4 v = ((const float4*)xs)[li];
    if (HALF) {
        f16x4 o;
        o.x = (f16)(2.f * v.x); o.y = (f16)(2.f * v.y);
        o.z = (f16)(2.f * v.z); o.w = (f16)(2.f * v.w);
        ((f16x4*)((f16*)hbase + (size_t)lvl * NN * 64))[li] = o;
    } else {
        ((float4*)((float*)hbase + (size_t)lvl * NN * 64))[li] =
            make_float4(2.f * v.x, 2.f * v.y, 2.f * v.z, 2.f * v.w);
    }
}

// ---------------- edge MLP + scatter-add: one 16-edge tile per WAVE, no LDS, no barriers ----------------
template<bool HALF>
__global__ __launch_bounds__(256) void edge_kernel(
    const float* __restrict__ x, const int* __restrict__ idx,
    const float* __restrict__ attr, const float* __restrict__ W,
    const float* __restrict__ b, void* __restrict__ hv) {

    const int t    = threadIdx.x;
    const int lane = t & 63;
    const int wid  = t >> 6;
    const int lr   = lane & 15;
    const int lg   = (lane >> 4) & 3;

    // W fragments resident in registers: wf[k0][n].j = W[k0*16+4*lg+j][n*16+lr]
    f16x4 wf[8][4];
#pragma unroll
    for (int k0 = 0; k0 < 8; ++k0) {
        const int kb = k0 * 16 + 4 * lg;
#pragma unroll
        for (int n = 0; n < 4; ++n) {
            const int c = n * 16 + lr;
            f16x4 w;
            w.x = (f16)W[(kb + 0) * 64 + c];
            w.y = (f16)W[(kb + 1) * 64 + c];
            w.z = (f16)W[(kb + 2) * 64 + c];
            w.w = (f16)W[(kb + 3) * 64 + c];
            wf[k0][n] = w;
        }
    }
    float bf[4];
#pragma unroll
    for (int n = 0; n < 4; ++n) bf[n] = b[n * 16 + lr];

    const float4* x4 = (const float4*)x;
    const float4* a4 = (const float4*)attr;

    const int gw     = blockIdx.x * 4 + wid;
    const int stride = gridDim.x * 4;
    for (int tile = gw; tile < ETILES; tile += stride) {
        const int e0  = tile << 4;
        const int src = idx[NE + e0 + lr];
        int tg[4];
#pragma unroll
        for (int j = 0; j < 4; ++j) tg[j] = idx[e0 + 4 * lg + j];

        // A fragments straight to registers: a[k0].j = A[lr][k0*16+4*lg+j]
        f16x4 a[8];
#pragma unroll
        for (int k0 = 0; k0 < 4; ++k0)
            a[k0] = cvt4(x4[(size_t)src * 16 + 4 * k0 + lg]);
#pragma unroll
        for (int k0 = 0; k0 < 4; ++k0)
            a[4 + k0] = cvt4(a4[(size_t)(e0 + lr) * 16 + 4 * k0 + lg]);

        f32x4 acc[4];
#pragma unroll
        for (int n = 0; n < 4; ++n) acc[n] = (f32x4){0.f, 0.f, 0.f, 0.f};
#pragma unroll
        for (int k0 = 0; k0 < 8; ++k0) {
#pragma unroll
            for (int n = 0; n < 4; ++n)
                acc[n] = __builtin_amdgcn_mfma_f32_16x16x16f16(a[k0], wf[k0][n], acc[n], 0, 0, 0);
        }

        // bias + relu + scatter. D[row=4*lg+j][col=n*16+lr].
#pragma unroll
        for (int j = 0; j < 4; ++j) {
            float v[4], vn[4];
#pragma unroll
            for (int n = 0; n < 4; ++n) v[n] = fmaxf(acc[n][j] + bf[n], 0.f);
#pragma unroll
            for (int n = 0; n < 4; ++n) vn[n] = __shfl_xor(v[n], 1);
            if (HALF) {
                __half* hp = (__half*)hv + (size_t)tg[j] * 64;
                if ((lane & 1) == 0) {   // even lane: columns (lr, lr+1) for n=0,1
                    unsafeAtomicAdd((__half2*)(hp + 0 * 16 + lr), __floats2half2_rn(v[0], vn[0]));
                    unsafeAtomicAdd((__half2*)(hp + 1 * 16 + lr), __floats2half2_rn(v[1], vn[1]));
                } else {                 // odd lane: columns (lr-1, lr) for n=2,3
                    unsafeAtomicAdd((__half2*)(hp + 2 * 16 + lr - 1), __floats2half2_rn(vn[2], v[2]));
                    unsafeAtomicAdd((__half2*)(hp + 3 * 16 + lr - 1), __floats2half2_rn(vn[3], v[3]));
                }
            } else {
                float* hp = (float*)hv + (size_t)tg[j] * 64;
#pragma unroll
                for (int n = 0; n < 4; ++n)
                    unsafeAtomicAdd(hp + n * 16 + lr, v[n]);
            }
        }
    }
}

// ---------------- node MLP: one 16-node tile per WAVE, per-wave LDS, no barriers ----------------
template<bool HALF>
__global__ __launch_bounds__(256) void node_kernel(
    const void* __restrict__ hbase, float* __restrict__ outb,
    const float* __restrict__ W1, const float* __restrict__ b1,
    const float* __restrict__ W2, const float* __restrict__ b2) {

    __shared__ f16 Y[4][16 * 72];   // per-wave y1 buffer, padded stride

    const int t    = threadIdx.x;
    const int lane = t & 63;
    const int wid  = t >> 6;
    const int lr   = lane & 15;
    const int lg   = (lane >> 4) & 3;

    f16x4 w1f[4][4], w2f[4][4];
#pragma unroll
    for (int k0 = 0; k0 < 4; ++k0) {
        const int kb = k0 * 16 + 4 * lg;
#pragma unroll
        for (int n = 0; n < 4; ++n) {
            const int c = n * 16 + lr;
            f16x4 w;
            w.x = (f16)W1[(kb + 0) * 64 + c];
            w.y = (f16)W1[(kb + 1) * 64 + c];
            w.z = (f16)W1[(kb + 2) * 64 + c];
            w.w = (f16)W1[(kb + 3) * 64 + c];
            w1f[k0][n] = w;
            w.x = (f16)W2[(kb + 0) * 64 + c];
            w.y = (f16)W2[(kb + 1) * 64 + c];
            w.z = (f16)W2[(kb + 2) * 64 + c];
            w.w = (f16)W2[(kb + 3) * 64 + c];
            w2f[k0][n] = w;
        }
    }
    float b1f[4], b2f[4];
#pragma unroll
    for (int n = 0; n < 4; ++n) {
        b1f[n] = b1[n * 16 + lr];
        b2f[n] = b2[n * 16 + lr];
    }

    const int gw     = blockIdx.x * 4 + wid;
    const int stride = gridDim.x * 4;
    for (int tile = gw; tile < 3 * NTILES; tile += stride) {
        const int lvl = tile / NTILES;
        const int n0  = (tile - lvl * NTILES) << 4;
        float* out = outb + (size_t)lvl * NN * 64;

        f16x4 a[4];
        if (HALF) {
            const f16* h16 = (const f16*)hbase + (size_t)lvl * NN * 64;
#pragma unroll
            for (int k0 = 0; k0 < 4; ++k0)
                a[k0] = *(const f16x4*)&h16[(size_t)(n0 + lr) * 64 + k0 * 16 + 4 * lg];
        } else {
            const float4* h4 = (const float4*)((const float*)hbase + (size_t)lvl * NN * 64);
#pragma unroll
            for (int k0 = 0; k0 < 4; ++k0)
                a[k0] = cvt4(h4[(size_t)(n0 + lr) * 16 + 4 * k0 + lg]);
        }

        f32x4 acc[4];
#pragma unroll
        for (int n = 0; n < 4; ++n) acc[n] = (f32x4){0.f, 0.f, 0.f, 0.f};
#pragma unroll
        for (int k0 = 0; k0 < 4; ++k0)
#pragma unroll
            for (int n = 0; n < 4; ++n)
                acc[n] = __builtin_amdgcn_mfma_f32_16x16x16f16(a[k0], w1f[k0][n], acc[n], 0, 0, 0);

        // y1 relu -> per-wave LDS (transposed to A layout); same-wave only, no barrier
#pragma unroll
        for (int n = 0; n < 4; ++n)
#pragma unroll
            for (int j = 0; j < 4; ++j) {
                float v = acc[n][j] + b1f[n];
                v = v > 0.f ? v : 0.f;
                Y[wid][(4 * lg + j) * 72 + n * 16 + lr] = (f16)v;
            }

        f16x4 a2[4];
#pragma unroll
        for (int k0 = 0; k0 < 4; ++k0)
            a2[k0] = *(const f16x4*)&Y[wid][lr * 72 + k0 * 16 + 4 * lg];

        f32x4 acc2[4];
#pragma unroll
        for (int n = 0; n < 4; ++n) acc2[n] = (f32x4){0.f, 0.f, 0.f, 0.f};
#pragma unroll
        for (int k0 = 0; k0 < 4; ++k0)
#pragma unroll
            for (int n = 0; n < 4; ++n)
                acc2[n] = __builtin_amdgcn_mfma_f32_16x16x16f16(a2[k0], w2f[k0][n], acc2[n], 0, 0, 0);

#pragma unroll
        for (int n = 0; n < 4; ++n)
#pragma unroll
            for (int j = 0; j < 4; ++j) {
                float v = acc2[n][j] + b2f[n];
                v = v > 0.f ? v : 0.f;
                out[(size_t)(n0 + 4 * lg + j) * 64 + n * 16 + lr] = v;
            }
    }
}

extern "C" void kernel_launch(void* const* d_in, const int* in_sizes, int n_in,
                              void* d_out, int out_size, void* d_ws, size_t ws_size,
                              hipStream_t stream) {
    (void)in_sizes; (void)n_in; (void)out_size;

    const float* W_up   = (const float*)d_in[15];
    const float* b_up   = (const float*)d_in[16];
    const float* W_down = (const float*)d_in[17];
    const float* b_down = (const float*)d_in[18];
    const float* W1     = (const float*)d_in[19];
    const float* b1     = (const float*)d_in[20];
    const float* W2     = (const float*)d_in[21];
    const float* b2     = (const float*)d_in[22];

    const float* x0 = (const float*)d_in[0];
    const float* x1 = (const float*)d_in[5];
    const float* x2 = (const float*)d_in[10];

    const bool half_ok = ws_size >= (size_t)3 * NN * 64 * sizeof(__half);

    if (half_ok) {
        f16* hbase = (f16*)d_ws;
        init_kernel<true><<<9375, 256, 0, stream>>>(x0, x1, x2, hbase);
        for (int d = 0; d < 3; ++d) {
            const float* x  = (const float*)d_in[5 * d + 0];
            const int*   ui = (const int*)  d_in[5 * d + 1];
            const int*   di = (const int*)  d_in[5 * d + 2];
            const float* ua = (const float*)d_in[5 * d + 3];
            const float* da = (const float*)d_in[5 * d + 4];
            void* h = hbase + (size_t)d * NN * 64;
            edge_kernel<true><<<1024, 256, 0, stream>>>(x, ui, ua, W_up,   b_up,   h);
            edge_kernel<true><<<1024, 256, 0, stream>>>(x, di, da, W_down, b_down, h);
        }
        node_kernel<true><<<586, 256, 0, stream>>>(hbase, (float*)d_out, W1, b1, W2, b2);
    } else {
        // fallback: f32 accumulation directly in d_out
        float* hbase = (float*)d_out;
        init_kernel<false><<<9375, 256, 0, stream>>>(x0, x1, x2, hbase);
        for (int d = 0; d < 3; ++d) {
            const float* x  = (const float*)d_in[5 * d + 0];
            const int*   ui = (const int*)  d_in[5 * d + 1];
            const int*   di = (const int*)  d_in[5 * d + 2];
            const float* ua = (const float*)d_in[5 * d + 3];
            const float* da = (const float*)d_in[5 * d + 4];
            void* h = hbase + (size_t)d * NN * 64;
            edge_kernel<false><<<1024, 256, 0, stream>>>(x, ui, ua, W_up,   b_up,   h);
            edge_kernel<false><<<1024, 256, 0, stream>>>(x, di, da, W_down, b_down, h);
        }
        node_kernel<false><<<586, 256, 0, stream>>>(hbase, (float*)d_out, W1, b1, W2, b2);
    }
}

// Round 4
// 443.066 us; speedup vs baseline: 1.9307x; 1.0581x over previous
//
#include <hip/hip_runtime.h>
#include <hip/hip_fp16.h>

#define NN 50000
#define NE 300000
#define ETILES (NE / 16)        // 18750
#define NTILES (NN / 16)        // 3125

typedef _Float16 f16;
typedef _Float16 f16x4 __attribute__((ext_vector_type(4)));
typedef float f32x4 __attribute__((ext_vector_type(4)));

__device__ __forceinline__ f16x4 cvt4(float4 v) {
    f16x4 r; r.x = (f16)v.x; r.y = (f16)v.y; r.z = (f16)v.z; r.w = (f16)v.w;
    return r;
}

// ---------------- init: h = 2*x for all 3 levels ----------------
template<bool HALF>
__global__ void init_kernel(const float* __restrict__ x0, const float* __restrict__ x1,
                            const float* __restrict__ x2, void* __restrict__ hbase) {
    const size_t i = (size_t)blockIdx.x * 256 + threadIdx.x;   // float4 index; 9375*256 == 3*NN*16
    const int lvl = (int)(i / (NN * 16));
    const size_t li = i - (size_t)lvl * (NN * 16);
    const float* xs = (lvl == 0) ? x0 : (lvl == 1) ? x1 : x2;
    float4 v = ((const float4*)xs)[li];
    if (HALF) {
        f16x4 o;
        o.x = (f16)(2.f * v.x); o.y = (f16)(2.f * v.y);
        o.z = (f16)(2.f * v.z); o.w = (f16)(2.f * v.w);
        ((f16x4*)((f16*)hbase + (size_t)lvl * NN * 64))[li] = o;
    } else {
        ((float4*)((float*)hbase + (size_t)lvl * NN * 64))[li] =
            make_float4(2.f * v.x, 2.f * v.y, 2.f * v.z, 2.f * v.w);
    }
}

// ---------------- W transpose: Wt[c][k] = (f16)W[k][c], W is [128][64] ----------------
__global__ void wtrans_kernel(const float* __restrict__ WU, const float* __restrict__ WD,
                              f16* __restrict__ WtU, f16* __restrict__ WtD) {
    const int i = blockIdx.x * 256 + threadIdx.x;   // 32 blocks * 256 = 8192
    const int k = i >> 6, c = i & 63;
    WtU[c * 128 + k] = (f16)WU[i];
    WtD[c * 128 + k] = (f16)WD[i];
}

// ---------------- edge MLP + scatter: both directions, 2-deep software pipeline ----------------
__global__ __launch_bounds__(256) void edge2_kernel(
    const float* __restrict__ x,
    const int* __restrict__ ui, const int* __restrict__ di,
    const float* __restrict__ ua, const float* __restrict__ da,
    const f16* __restrict__ WtU, const f16* __restrict__ WtD,
    const float* __restrict__ bU, const float* __restrict__ bD,
    __half* __restrict__ h) {

    const int dir = blockIdx.y;
    const int* __restrict__ idx   = dir ? di : ui;
    const float* __restrict__ attr = dir ? da : ua;
    const f16* __restrict__ Wt    = dir ? WtD : WtU;
    const float* __restrict__ b   = dir ? bD : bU;

    const int t    = threadIdx.x;
    const int lane = t & 63;
    const int wid  = t >> 6;
    const int lr   = lane & 15;
    const int lg   = (lane >> 4) & 3;
    const int l5   = lane & 31;

    // W fragments: wf[k0][n].j = W[k0*16+4*lg+j][n*16+lr] = Wt[(n*16+lr)*128 + k0*16+4*lg + j]
    f16x4 wf[8][4];
#pragma unroll
    for (int k0 = 0; k0 < 8; ++k0)
#pragma unroll
        for (int n = 0; n < 4; ++n)
            wf[k0][n] = *(const f16x4*)&Wt[(n * 16 + lr) * 128 + k0 * 16 + 4 * lg];
    float bf[4];
#pragma unroll
    for (int n = 0; n < 4; ++n) bf[n] = b[n * 16 + lr];

    const float4* x4 = (const float4*)x;
    const float4* a4 = (const float4*)attr;

    const int gw     = blockIdx.x * 4 + wid;
    const int stride = gridDim.x * 4;

    int tile = gw;
    if (tile >= ETILES) return;

    // prologue: idx + attr for first tile
    int comb;            // lanes 0-15: src, lanes 16-31: tgt (dup in upper half-wave)
    float4 pA[4];
    {
        const int e0 = tile << 4;
        comb = idx[(l5 < 16) ? (NE + e0 + l5) : (e0 + l5 - 16)];
#pragma unroll
        for (int k0 = 0; k0 < 4; ++k0)
            pA[k0] = a4[(size_t)(e0 + lr) * 16 + 4 * k0 + lg];
    }

    for (; tile < ETILES; tile += stride) {
        const int src = __shfl(comb, lr);
        int tg[4];
#pragma unroll
        for (int j = 0; j < 4; ++j) tg[j] = __shfl(comb, 16 + 4 * lg + j);

        // issue x gather for current tile (only in-tile dependency)
        float4 gx[4];
#pragma unroll
        for (int k0 = 0; k0 < 4; ++k0)
            gx[k0] = x4[(size_t)src * 16 + 4 * k0 + lg];

        // prefetch idx + attr for NEXT tile (independent, overlaps MFMA/atomics)
        const int tn = tile + stride;
        int combN = 0;
        float4 pAn[4] = {};
        if (tn < ETILES) {
            const int e0n = tn << 4;
            combN = idx[(l5 < 16) ? (NE + e0n + l5) : (e0n + l5 - 16)];
#pragma unroll
            for (int k0 = 0; k0 < 4; ++k0)
                pAn[k0] = a4[(size_t)(e0n + lr) * 16 + 4 * k0 + lg];
        }

        // fragments: a[k0].j = A[lr][k0*16+4*lg+j]
        f16x4 a[8];
#pragma unroll
        for (int k0 = 0; k0 < 4; ++k0) a[4 + k0] = cvt4(pA[k0]);   // attr (already arrived)
#pragma unroll
        for (int k0 = 0; k0 < 4; ++k0) a[k0] = cvt4(gx[k0]);       // waits on gather only

        f32x4 acc[4];
#pragma unroll
        for (int n = 0; n < 4; ++n) acc[n] = (f32x4){0.f, 0.f, 0.f, 0.f};
#pragma unroll
        for (int k0 = 0; k0 < 8; ++k0)
#pragma unroll
            for (int n = 0; n < 4; ++n)
                acc[n] = __builtin_amdgcn_mfma_f32_16x16x16f16(a[k0], wf[k0][n], acc[n], 0, 0, 0);

        // bias + relu + packed f16 atomic scatter. D[row=4*lg+j][col=n*16+lr].
#pragma unroll
        for (int j = 0; j < 4; ++j) {
            float v[4], vn[4];
#pragma unroll
            for (int n = 0; n < 4; ++n) v[n] = fmaxf(acc[n][j] + bf[n], 0.f);
#pragma unroll
            for (int n = 0; n < 4; ++n) vn[n] = __shfl_xor(v[n], 1);
            __half* hp = h + (size_t)tg[j] * 64;
            if ((lane & 1) == 0) {
                unsafeAtomicAdd((__half2*)(hp + 0 * 16 + lr), __floats2half2_rn(v[0], vn[0]));
                unsafeAtomicAdd((__half2*)(hp + 1 * 16 + lr), __floats2half2_rn(v[1], vn[1]));
            } else {
                unsafeAtomicAdd((__half2*)(hp + 2 * 16 + lr - 1), __floats2half2_rn(vn[2], v[2]));
                unsafeAtomicAdd((__half2*)(hp + 3 * 16 + lr - 1), __floats2half2_rn(vn[3], v[3]));
            }
        }

        comb = combN;
#pragma unroll
        for (int k0 = 0; k0 < 4; ++k0) pA[k0] = pAn[k0];
    }
}

// ---------------- fallback edge kernel (f32 accumulation in d_out) ----------------
__global__ __launch_bounds__(256) void edge_f32_kernel(
    const float* __restrict__ x, const int* __restrict__ idx,
    const float* __restrict__ attr, const float* __restrict__ W,
    const float* __restrict__ b, float* __restrict__ h) {

    const int t    = threadIdx.x;
    const int lane = t & 63;
    const int wid  = t >> 6;
    const int lr   = lane & 15;
    const int lg   = (lane >> 4) & 3;

    f16x4 wf[8][4];
#pragma unroll
    for (int k0 = 0; k0 < 8; ++k0) {
        const int kb = k0 * 16 + 4 * lg;
#pragma unroll
        for (int n = 0; n < 4; ++n) {
            const int c = n * 16 + lr;
            f16x4 w;
            w.x = (f16)W[(kb + 0) * 64 + c];
            w.y = (f16)W[(kb + 1) * 64 + c];
            w.z = (f16)W[(kb + 2) * 64 + c];
            w.w = (f16)W[(kb + 3) * 64 + c];
            wf[k0][n] = w;
        }
    }
    float bf[4];
#pragma unroll
    for (int n = 0; n < 4; ++n) bf[n] = b[n * 16 + lr];

    const float4* x4 = (const float4*)x;
    const float4* a4 = (const float4*)attr;

    const int gw     = blockIdx.x * 4 + wid;
    const int stride = gridDim.x * 4;
    for (int tile = gw; tile < ETILES; tile += stride) {
        const int e0  = tile << 4;
        const int src = idx[NE + e0 + lr];
        int tg[4];
#pragma unroll
        for (int j = 0; j < 4; ++j) tg[j] = idx[e0 + 4 * lg + j];

        f16x4 a[8];
#pragma unroll
        for (int k0 = 0; k0 < 4; ++k0)
            a[k0] = cvt4(x4[(size_t)src * 16 + 4 * k0 + lg]);
#pragma unroll
        for (int k0 = 0; k0 < 4; ++k0)
            a[4 + k0] = cvt4(a4[(size_t)(e0 + lr) * 16 + 4 * k0 + lg]);

        f32x4 acc[4];
#pragma unroll
        for (int n = 0; n < 4; ++n) acc[n] = (f32x4){0.f, 0.f, 0.f, 0.f};
#pragma unroll
        for (int k0 = 0; k0 < 8; ++k0)
#pragma unroll
            for (int n = 0; n < 4; ++n)
                acc[n] = __builtin_amdgcn_mfma_f32_16x16x16f16(a[k0], wf[k0][n], acc[n], 0, 0, 0);

#pragma unroll
        for (int j = 0; j < 4; ++j) {
            float* hp = h + (size_t)tg[j] * 64;
#pragma unroll
            for (int n = 0; n < 4; ++n) {
                float v = fmaxf(acc[n][j] + bf[n], 0.f);
                unsafeAtomicAdd(hp + n * 16 + lr, v);
            }
        }
    }
}

// ---------------- node MLP: one 16-node tile per WAVE, per-wave LDS, no barriers ----------------
template<bool HALF>
__global__ __launch_bounds__(256) void node_kernel(
    const void* __restrict__ hbase, float* __restrict__ outb,
    const float* __restrict__ W1, const float* __restrict__ b1,
    const float* __restrict__ W2, const float* __restrict__ b2) {

    __shared__ f16 Y[4][16 * 72];

    const int t    = threadIdx.x;
    const int lane = t & 63;
    const int wid  = t >> 6;
    const int lr   = lane & 15;
    const int lg   = (lane >> 4) & 3;

    f16x4 w1f[4][4], w2f[4][4];
#pragma unroll
    for (int k0 = 0; k0 < 4; ++k0) {
        const int kb = k0 * 16 + 4 * lg;
#pragma unroll
        for (int n = 0; n < 4; ++n) {
            const int c = n * 16 + lr;
            f16x4 w;
            w.x = (f16)W1[(kb + 0) * 64 + c];
            w.y = (f16)W1[(kb + 1) * 64 + c];
            w.z = (f16)W1[(kb + 2) * 64 + c];
            w.w = (f16)W1[(kb + 3) * 64 + c];
            w1f[k0][n] = w;
            w.x = (f16)W2[(kb + 0) * 64 + c];
            w.y = (f16)W2[(kb + 1) * 64 + c];
            w.z = (f16)W2[(kb + 2) * 64 + c];
            w.w = (f16)W2[(kb + 3) * 64 + c];
            w2f[k0][n] = w;
        }
    }
    float b1f[4], b2f[4];
#pragma unroll
    for (int n = 0; n < 4; ++n) {
        b1f[n] = b1[n * 16 + lr];
        b2f[n] = b2[n * 16 + lr];
    }

    const int gw     = blockIdx.x * 4 + wid;
    const int stride = gridDim.x * 4;
    for (int tile = gw; tile < 3 * NTILES; tile += stride) {
        const int lvl = tile / NTILES;
        const int n0  = (tile - lvl * NTILES) << 4;
        float* out = outb + (size_t)lvl * NN * 64;

        f16x4 a[4];
        if (HALF) {
            const f16* h16 = (const f16*)hbase + (size_t)lvl * NN * 64;
#pragma unroll
            for (int k0 = 0; k0 < 4; ++k0)
                a[k0] = *(const f16x4*)&h16[(size_t)(n0 + lr) * 64 + k0 * 16 + 4 * lg];
        } else {
            const float4* h4 = (const float4*)((const float*)hbase + (size_t)lvl * NN * 64);
#pragma unroll
            for (int k0 = 0; k0 < 4; ++k0)
                a[k0] = cvt4(h4[(size_t)(n0 + lr) * 16 + 4 * k0 + lg]);
        }

        f32x4 acc[4];
#pragma unroll
        for (int n = 0; n < 4; ++n) acc[n] = (f32x4){0.f, 0.f, 0.f, 0.f};
#pragma unroll
        for (int k0 = 0; k0 < 4; ++k0)
#pragma unroll
            for (int n = 0; n < 4; ++n)
                acc[n] = __builtin_amdgcn_mfma_f32_16x16x16f16(a[k0], w1f[k0][n], acc[n], 0, 0, 0);

#pragma unroll
        for (int n = 0; n < 4; ++n)
#pragma unroll
            for (int j = 0; j < 4; ++j) {
                float v = acc[n][j] + b1f[n];
                v = v > 0.f ? v : 0.f;
                Y[wid][(4 * lg + j) * 72 + n * 16 + lr] = (f16)v;
            }

        f16x4 a2[4];
#pragma unroll
        for (int k0 = 0; k0 < 4; ++k0)
            a2[k0] = *(const f16x4*)&Y[wid][lr * 72 + k0 * 16 + 4 * lg];

        f32x4 acc2[4];
#pragma unroll
        for (int n = 0; n < 4; ++n) acc2[n] = (f32x4){0.f, 0.f, 0.f, 0.f};
#pragma unroll
        for (int k0 = 0; k0 < 4; ++k0)
#pragma unroll
            for (int n = 0; n < 4; ++n)
                acc2[n] = __builtin_amdgcn_mfma_f32_16x16x16f16(a2[k0], w2f[k0][n], acc2[n], 0, 0, 0);

#pragma unroll
        for (int n = 0; n < 4; ++n)
#pragma unroll
            for (int j = 0; j < 4; ++j) {
                float v = acc2[n][j] + b2f[n];
                v = v > 0.f ? v : 0.f;
                out[(size_t)(n0 + 4 * lg + j) * 64 + n * 16 + lr] = v;
            }
    }
}

extern "C" void kernel_launch(void* const* d_in, const int* in_sizes, int n_in,
                              void* d_out, int out_size, void* d_ws, size_t ws_size,
                              hipStream_t stream) {
    (void)in_sizes; (void)n_in; (void)out_size;

    const float* W_up   = (const float*)d_in[15];
    const float* b_up   = (const float*)d_in[16];
    const float* W_down = (const float*)d_in[17];
    const float* b_down = (const float*)d_in[18];
    const float* W1     = (const float*)d_in[19];
    const float* b1     = (const float*)d_in[20];
    const float* W2     = (const float*)d_in[21];
    const float* b2     = (const float*)d_in[22];

    const float* x0 = (const float*)d_in[0];
    const float* x1 = (const float*)d_in[5];
    const float* x2 = (const float*)d_in[10];

    const size_t hbytes = (size_t)3 * NN * 64 * sizeof(__half);   // 19.2 MB
    const bool half_ok = ws_size >= hbytes + 2 * 128 * 64 * sizeof(f16);

    if (half_ok) {
        f16* hbase = (f16*)d_ws;
        f16* WtU = (f16*)((char*)d_ws + hbytes);
        f16* WtD = WtU + 128 * 64;

        wtrans_kernel<<<32, 256, 0, stream>>>(W_up, W_down, WtU, WtD);
        init_kernel<true><<<9375, 256, 0, stream>>>(x0, x1, x2, hbase);
        for (int d = 0; d < 3; ++d) {
            const float* x  = (const float*)d_in[5 * d + 0];
            const int*   ui = (const int*)  d_in[5 * d + 1];
            const int*   di = (const int*)  d_in[5 * d + 2];
            const float* ua = (const float*)d_in[5 * d + 3];
            const float* da = (const float*)d_in[5 * d + 4];
            __half* h = (__half*)(hbase + (size_t)d * NN * 64);
            edge2_kernel<<<dim3(1024, 2), 256, 0, stream>>>(
                x, ui, di, ua, da, WtU, WtD, b_up, b_down, h);
        }
        node_kernel<true><<<586, 256, 0, stream>>>(hbase, (float*)d_out, W1, b1, W2, b2);
    } else {
        float* hbase = (float*)d_out;
        init_kernel<false><<<9375, 256, 0, stream>>>(x0, x1, x2, hbase);
        for (int d = 0; d < 3; ++d) {
            const float* x  = (const float*)d_in[5 * d + 0];
            const int*   ui = (const int*)  d_in[5 * d + 1];
            const int*   di = (const int*)  d_in[5 * d + 2];
            const float* ua = (const float*)d_in[5 * d + 3];
            const float* da = (const float*)d_in[5 * d + 4];
            float* h = hbase + (size_t)d * NN * 64;
            edge_f32_kernel<<<1024, 256, 0, stream>>>(x, ui, ua, W_up,   b_up,   h);
            edge_f32_kernel<<<1024, 256, 0, stream>>>(x, di, da, W_down, b_down, h);
        }
        node_kernel<false><<<586, 256, 0, stream>>>(hbase, (float*)d_out, W1, b1, W2, b2);
    }
}

// Round 5
// 433.822 us; speedup vs baseline: 1.9718x; 1.0213x over previous
//
#include <hip/hip_runtime.h>
#include <hip/hip_fp16.h>

#define NN 50000
#define NE 300000
#define ETILES (NE / 16)        // 18750
#define NTILES (NN / 16)        // 3125

typedef _Float16 f16;
typedef _Float16 f16x4 __attribute__((ext_vector_type(4)));
typedef _Float16 f16x8 __attribute__((ext_vector_type(8)));
typedef float f32x4 __attribute__((ext_vector_type(4)));

__device__ __forceinline__ f16x4 cvt4(float4 v) {
    f16x4 r; r.x = (f16)v.x; r.y = (f16)v.y; r.z = (f16)v.z; r.w = (f16)v.w;
    return r;
}

// ---------------- init (full path): h = 2*x (f16) AND xh = x (f16), 3 levels ----------------
__global__ void init2_kernel(const float* __restrict__ x0, const float* __restrict__ x1,
                             const float* __restrict__ x2,
                             f16* __restrict__ hbase, f16* __restrict__ xhbase) {
    const size_t i = (size_t)blockIdx.x * 256 + threadIdx.x;   // float4 idx; 9375*256 == 3*NN*16
    const int lvl = (int)(i / (NN * 16));
    const size_t li = i - (size_t)lvl * (NN * 16);
    const float* xs = (lvl == 0) ? x0 : (lvl == 1) ? x1 : x2;
    float4 v = ((const float4*)xs)[li];
    f16x4 xo, ho;
    xo.x = (f16)v.x;        xo.y = (f16)v.y;        xo.z = (f16)v.z;        xo.w = (f16)v.w;
    ho.x = (f16)(2.f*v.x);  ho.y = (f16)(2.f*v.y);  ho.z = (f16)(2.f*v.z);  ho.w = (f16)(2.f*v.w);
    ((f16x4*)(xhbase + (size_t)lvl * NN * 64))[li] = xo;
    ((f16x4*)(hbase  + (size_t)lvl * NN * 64))[li] = ho;
}

// ---------------- init (fallback): h = 2*x (f32) in d_out ----------------
__global__ void initf32_kernel(const float* __restrict__ x0, const float* __restrict__ x1,
                               const float* __restrict__ x2, float* __restrict__ hbase) {
    const size_t i = (size_t)blockIdx.x * 256 + threadIdx.x;
    const int lvl = (int)(i / (NN * 16));
    const size_t li = i - (size_t)lvl * (NN * 16);
    const float* xs = (lvl == 0) ? x0 : (lvl == 1) ? x1 : x2;
    float4 v = ((const float4*)xs)[li];
    ((float4*)(hbase + (size_t)lvl * NN * 64))[li] =
        make_float4(2.f * v.x, 2.f * v.y, 2.f * v.z, 2.f * v.w);
}

// ---------------- W transpose: Wt[c][k] = (f16)W[k][c], W is [128][64] ----------------
__global__ void wtrans_kernel(const float* __restrict__ WU, const float* __restrict__ WD,
                              f16* __restrict__ WtU, f16* __restrict__ WtD) {
    const int i = blockIdx.x * 256 + threadIdx.x;   // 32 blocks * 256 = 8192
    const int k = i >> 6, c = i & 63;
    WtU[c * 128 + k] = (f16)WU[i];
    WtD[c * 128 + k] = (f16)WD[i];
}

// ---------------- edge MLP + scatter: f16 x, W in LDS, 2-deep pipeline ----------------
#define WLDS_STRIDE 136   // 128 + 8 f16 pad -> 272B row stride, bank-stride 4

__device__ __forceinline__ int ld_comb(const int* __restrict__ idx, int tile, int l5) {
    const int e0 = tile << 4;
    return idx[(l5 < 16) ? (NE + e0 + l5) : (e0 + l5 - 16)];
}

__global__ __launch_bounds__(256) void edge4_kernel(
    const f16* __restrict__ xh,
    const int* __restrict__ ui, const int* __restrict__ di,
    const float* __restrict__ ua, const float* __restrict__ da,
    const f16* __restrict__ WtU, const f16* __restrict__ WtD,
    const float* __restrict__ bU, const float* __restrict__ bD,
    __half* __restrict__ h) {

    __shared__ __align__(16) f16 Wlds[64 * WLDS_STRIDE];

    const int dir = blockIdx.y;
    const int* __restrict__ idx    = dir ? di : ui;
    const float* __restrict__ attr = dir ? da : ua;
    const f16* __restrict__ Wt     = dir ? WtD : WtU;
    const float* __restrict__ b    = dir ? bD : bU;

    const int tt   = threadIdx.x;
    const int lane = tt & 63;
    const int wid  = tt >> 6;
    const int lr   = lane & 15;
    const int lg   = (lane >> 4) & 3;
    const int l5   = lane & 31;

    // stage W into LDS (64 rows x 128 f16, padded stride)
    for (int i = tt; i < 1024; i += 256) {           // 64 rows * 16 segs of f16x8
        const int row = i >> 4, seg = i & 15;
        *(f16x8*)&Wlds[row * WLDS_STRIDE + seg * 8] = *(const f16x8*)&Wt[row * 128 + seg * 8];
    }
    float bf[4];
#pragma unroll
    for (int n = 0; n < 4; ++n) bf[n] = b[n * 16 + lr];
    __syncthreads();

    const float4* a4 = (const float4*)attr;

    const int S = gridDim.x * 4;
    int t = blockIdx.x * 4 + wid;
    if (t >= ETILES) return;

    // prologue: comb for tiles t and t+S; gather + attr for tile t
    int cB;
    int srcT, tgT[4];
    f16x4 gx[4];
    float4 pA[4];
    {
        const int cA = ld_comb(idx, t, l5);
        const int tn1 = t + S;
        cB = ld_comb(idx, (tn1 < ETILES) ? tn1 : t, l5);
        srcT = __shfl(cA, lr);
#pragma unroll
        for (int j = 0; j < 4; ++j) tgT[j] = __shfl(cA, 16 + 4 * lg + j);
        const int e0 = t << 4;
#pragma unroll
        for (int k0 = 0; k0 < 4; ++k0)
            gx[k0] = *(const f16x4*)&xh[(size_t)srcT * 64 + k0 * 16 + 4 * lg];
#pragma unroll
        for (int k0 = 0; k0 < 4; ++k0)
            pA[k0] = a4[(size_t)(e0 + lr) * 16 + 4 * k0 + lg];
    }

    for (; t < ETILES; t += S) {
        const int tn  = t + S;
        const int tnn = tn + S;

        // decode next tile's indices (cB arrived ~1 iter ago), issue next-next idx
        const int srcN = __shfl(cB, lr);
        int tgN[4];
#pragma unroll
        for (int j = 0; j < 4; ++j) tgN[j] = __shfl(cB, 16 + 4 * lg + j);
        const int cC = ld_comb(idx, (tnn < ETILES) ? tnn : t, l5);

        // issue next tile's gather + attr (clamped when past end; results unused)
        const int tnc   = (tn < ETILES) ? tn : t;
        const int srcNc = (tn < ETILES) ? srcN : srcT;
        f16x4 gxN[4];
        float4 pAN[4];
        {
            const int e0n = tnc << 4;
#pragma unroll
            for (int k0 = 0; k0 < 4; ++k0)
                gxN[k0] = *(const f16x4*)&xh[(size_t)srcNc * 64 + k0 * 16 + 4 * lg];
#pragma unroll
            for (int k0 = 0; k0 < 4; ++k0)
                pAN[k0] = a4[(size_t)(e0n + lr) * 16 + 4 * k0 + lg];
        }

        // fragments for current tile
        f16x4 afr[8];
#pragma unroll
        for (int k0 = 0; k0 < 4; ++k0) afr[k0] = gx[k0];
#pragma unroll
        for (int k0 = 0; k0 < 4; ++k0) afr[4 + k0] = cvt4(pA[k0]);

        f32x4 acc[4];
#pragma unroll
        for (int n = 0; n < 4; ++n) acc[n] = (f32x4){0.f, 0.f, 0.f, 0.f};
#pragma unroll
        for (int k0 = 0; k0 < 8; ++k0) {
#pragma unroll
            for (int n = 0; n < 4; ++n) {
                const f16x4 wf = *(const f16x4*)&Wlds[(n * 16 + lr) * WLDS_STRIDE + k0 * 16 + 4 * lg];
                acc[n] = __builtin_amdgcn_mfma_f32_16x16x16f16(afr[k0], wf, acc[n], 0, 0, 0);
            }
        }

        // bias + relu + packed f16 atomic scatter. D[row=4*lg+j][col=n*16+lr].
#pragma unroll
        for (int j = 0; j < 4; ++j) {
            float v[4], vn[4];
#pragma unroll
            for (int n = 0; n < 4; ++n) v[n] = fmaxf(acc[n][j] + bf[n], 0.f);
#pragma unroll
            for (int n = 0; n < 4; ++n) vn[n] = __shfl_xor(v[n], 1);
            __half* hp = h + (size_t)tgT[j] * 64;
            if ((lane & 1) == 0) {
                unsafeAtomicAdd((__half2*)(hp + 0 * 16 + lr), __floats2half2_rn(v[0], vn[0]));
                unsafeAtomicAdd((__half2*)(hp + 1 * 16 + lr), __floats2half2_rn(v[1], vn[1]));
            } else {
                unsafeAtomicAdd((__half2*)(hp + 2 * 16 + lr - 1), __floats2half2_rn(vn[2], v[2]));
                unsafeAtomicAdd((__half2*)(hp + 3 * 16 + lr - 1), __floats2half2_rn(vn[3], v[3]));
            }
        }

        // shift pipeline state
        srcT = srcN;
#pragma unroll
        for (int j = 0; j < 4; ++j) tgT[j] = tgN[j];
#pragma unroll
        for (int k0 = 0; k0 < 4; ++k0) { gx[k0] = gxN[k0]; pA[k0] = pAN[k0]; }
        cB = cC;
    }
}

// ---------------- fallback edge kernel (f32 accumulation in d_out) ----------------
__global__ __launch_bounds__(256) void edge_f32_kernel(
    const float* __restrict__ x, const int* __restrict__ idx,
    const float* __restrict__ attr, const float* __restrict__ W,
    const float* __restrict__ b, float* __restrict__ h) {

    const int t    = threadIdx.x;
    const int lane = t & 63;
    const int wid  = t >> 6;
    const int lr   = lane & 15;
    const int lg   = (lane >> 4) & 3;

    f16x4 wf[8][4];
#pragma unroll
    for (int k0 = 0; k0 < 8; ++k0) {
        const int kb = k0 * 16 + 4 * lg;
#pragma unroll
        for (int n = 0; n < 4; ++n) {
            const int c = n * 16 + lr;
            f16x4 w;
            w.x = (f16)W[(kb + 0) * 64 + c];
            w.y = (f16)W[(kb + 1) * 64 + c];
            w.z = (f16)W[(kb + 2) * 64 + c];
            w.w = (f16)W[(kb + 3) * 64 + c];
            wf[k0][n] = w;
        }
    }
    float bf[4];
#pragma unroll
    for (int n = 0; n < 4; ++n) bf[n] = b[n * 16 + lr];

    const float4* x4 = (const float4*)x;
    const float4* a4 = (const float4*)attr;

    const int gw     = blockIdx.x * 4 + wid;
    const int stride = gridDim.x * 4;
    for (int tile = gw; tile < ETILES; tile += stride) {
        const int e0  = tile << 4;
        const int src = idx[NE + e0 + lr];
        int tg[4];
#pragma unroll
        for (int j = 0; j < 4; ++j) tg[j] = idx[e0 + 4 * lg + j];

        f16x4 a[8];
#pragma unroll
        for (int k0 = 0; k0 < 4; ++k0)
            a[k0] = cvt4(x4[(size_t)src * 16 + 4 * k0 + lg]);
#pragma unroll
        for (int k0 = 0; k0 < 4; ++k0)
            a[4 + k0] = cvt4(a4[(size_t)(e0 + lr) * 16 + 4 * k0 + lg]);

        f32x4 acc[4];
#pragma unroll
        for (int n = 0; n < 4; ++n) acc[n] = (f32x4){0.f, 0.f, 0.f, 0.f};
#pragma unroll
        for (int k0 = 0; k0 < 8; ++k0)
#pragma unroll
            for (int n = 0; n < 4; ++n)
                acc[n] = __builtin_amdgcn_mfma_f32_16x16x16f16(a[k0], wf[k0][n], acc[n], 0, 0, 0);

#pragma unroll
        for (int j = 0; j < 4; ++j) {
            float* hp = h + (size_t)tg[j] * 64;
#pragma unroll
            for (int n = 0; n < 4; ++n) {
                float v = fmaxf(acc[n][j] + bf[n], 0.f);
                unsafeAtomicAdd(hp + n * 16 + lr, v);
            }
        }
    }
}

// ---------------- node MLP: one 16-node tile per WAVE, per-wave LDS, no barriers ----------------
template<bool HALF>
__global__ __launch_bounds__(256) void node_kernel(
    const void* __restrict__ hbase, float* __restrict__ outb,
    const float* __restrict__ W1, const float* __restrict__ b1,
    const float* __restrict__ W2, const float* __restrict__ b2) {

    __shared__ f16 Y[4][16 * 72];

    const int t    = threadIdx.x;
    const int lane = t & 63;
    const int wid  = t >> 6;
    const int lr   = lane & 15;
    const int lg   = (lane >> 4) & 3;

    f16x4 w1f[4][4], w2f[4][4];
#pragma unroll
    for (int k0 = 0; k0 < 4; ++k0) {
        const int kb = k0 * 16 + 4 * lg;
#pragma unroll
        for (int n = 0; n < 4; ++n) {
            const int c = n * 16 + lr;
            f16x4 w;
            w.x = (f16)W1[(kb + 0) * 64 + c];
            w.y = (f16)W1[(kb + 1) * 64 + c];
            w.z = (f16)W1[(kb + 2) * 64 + c];
            w.w = (f16)W1[(kb + 3) * 64 + c];
            w1f[k0][n] = w;
            w.x = (f16)W2[(kb + 0) * 64 + c];
            w.y = (f16)W2[(kb + 1) * 64 + c];
            w.z = (f16)W2[(kb + 2) * 64 + c];
            w.w = (f16)W2[(kb + 3) * 64 + c];
            w2f[k0][n] = w;
        }
    }
    float b1f[4], b2f[4];
#pragma unroll
    for (int n = 0; n < 4; ++n) {
        b1f[n] = b1[n * 16 + lr];
        b2f[n] = b2[n * 16 + lr];
    }

    const int gw     = blockIdx.x * 4 + wid;
    const int stride = gridDim.x * 4;
    for (int tile = gw; tile < 3 * NTILES; tile += stride) {
        const int lvl = tile / NTILES;
        const int n0  = (tile - lvl * NTILES) << 4;
        float* out = outb + (size_t)lvl * NN * 64;

        f16x4 a[4];
        if (HALF) {
            const f16* h16 = (const f16*)hbase + (size_t)lvl * NN * 64;
#pragma unroll
            for (int k0 = 0; k0 < 4; ++k0)
                a[k0] = *(const f16x4*)&h16[(size_t)(n0 + lr) * 64 + k0 * 16 + 4 * lg];
        } else {
            const float4* h4 = (const float4*)((const float*)hbase + (size_t)lvl * NN * 64);
#pragma unroll
            for (int k0 = 0; k0 < 4; ++k0)
                a[k0] = cvt4(h4[(size_t)(n0 + lr) * 16 + 4 * k0 + lg]);
        }

        f32x4 acc[4];
#pragma unroll
        for (int n = 0; n < 4; ++n) acc[n] = (f32x4){0.f, 0.f, 0.f, 0.f};
#pragma unroll
        for (int k0 = 0; k0 < 4; ++k0)
#pragma unroll
            for (int n = 0; n < 4; ++n)
                acc[n] = __builtin_amdgcn_mfma_f32_16x16x16f16(a[k0], w1f[k0][n], acc[n], 0, 0, 0);

#pragma unroll
        for (int n = 0; n < 4; ++n)
#pragma unroll
            for (int j = 0; j < 4; ++j) {
                float v = acc[n][j] + b1f[n];
                v = v > 0.f ? v : 0.f;
                Y[wid][(4 * lg + j) * 72 + n * 16 + lr] = (f16)v;
            }

        f16x4 a2[4];
#pragma unroll
        for (int k0 = 0; k0 < 4; ++k0)
            a2[k0] = *(const f16x4*)&Y[wid][lr * 72 + k0 * 16 + 4 * lg];

        f32x4 acc2[4];
#pragma unroll
        for (int n = 0; n < 4; ++n) acc2[n] = (f32x4){0.f, 0.f, 0.f, 0.f};
#pragma unroll
        for (int k0 = 0; k0 < 4; ++k0)
#pragma unroll
            for (int n = 0; n < 4; ++n)
                acc2[n] = __builtin_amdgcn_mfma_f32_16x16x16f16(a2[k0], w2f[k0][n], acc2[n], 0, 0, 0);

#pragma unroll
        for (int n = 0; n < 4; ++n)
#pragma unroll
            for (int j = 0; j < 4; ++j) {
                float v = acc2[n][j] + b2f[n];
                v = v > 0.f ? v : 0.f;
                out[(size_t)(n0 + 4 * lg + j) * 64 + n * 16 + lr] = v;
            }
    }
}

extern "C" void kernel_launch(void* const* d_in, const int* in_sizes, int n_in,
                              void* d_out, int out_size, void* d_ws, size_t ws_size,
                              hipStream_t stream) {
    (void)in_sizes; (void)n_in; (void)out_size;

    const float* W_up   = (const float*)d_in[15];
    const float* b_up   = (const float*)d_in[16];
    const float* W_down = (const float*)d_in[17];
    const float* b_down = (const float*)d_in[18];
    const float* W1     = (const float*)d_in[19];
    const float* b1     = (const float*)d_in[20];
    const float* W2     = (const float*)d_in[21];
    const float* b2     = (const float*)d_in[22];

    const float* x0 = (const float*)d_in[0];
    const float* x1 = (const float*)d_in[5];
    const float* x2 = (const float*)d_in[10];

    const size_t hbytes  = (size_t)3 * NN * 64 * sizeof(f16);   // 19.2 MB
    const size_t need    = 2 * hbytes + (size_t)2 * 128 * 64 * sizeof(f16);

    if (ws_size >= need) {
        f16* hbase  = (f16*)d_ws;
        f16* xhbase = hbase + (size_t)3 * NN * 64;
        f16* WtU    = (f16*)((char*)d_ws + 2 * hbytes);
        f16* WtD    = WtU + 128 * 64;

        wtrans_kernel<<<32, 256, 0, stream>>>(W_up, W_down, WtU, WtD);
        init2_kernel<<<9375, 256, 0, stream>>>(x0, x1, x2, hbase, xhbase);
        for (int d = 0; d < 3; ++d) {
            const int*   ui = (const int*)  d_in[5 * d + 1];
            const int*   di = (const int*)  d_in[5 * d + 2];
            const float* ua = (const float*)d_in[5 * d + 3];
            const float* da = (const float*)d_in[5 * d + 4];
            const f16* xh = xhbase + (size_t)d * NN * 64;
            __half* h = (__half*)(hbase + (size_t)d * NN * 64);
            edge4_kernel<<<dim3(1024, 2), 256, 0, stream>>>(
                xh, ui, di, ua, da, WtU, WtD, b_up, b_down, h);
        }
        node_kernel<true><<<586, 256, 0, stream>>>(hbase, (float*)d_out, W1, b1, W2, b2);
    } else {
        float* hbase = (float*)d_out;
        initf32_kernel<<<9375, 256, 0, stream>>>(x0, x1, x2, hbase);
        for (int d = 0; d < 3; ++d) {
            const float* x  = (const float*)d_in[5 * d + 0];
            const int*   ui = (const int*)  d_in[5 * d + 1];
            const int*   di = (const int*)  d_in[5 * d + 2];
            const float* ua = (const float*)d_in[5 * d + 3];
            const float* da = (const float*)d_in[5 * d + 4];
            float* h = hbase + (size_t)d * NN * 64;
            edge_f32_kernel<<<1024, 256, 0, stream>>>(x, ui, ua, W_up,   b_up,   h);
            edge_f32_kernel<<<1024, 256, 0, stream>>>(x, di, da, W_down, b_down, h);
        }
        node_kernel<false><<<586, 256, 0, stream>>>(hbase, (float*)d_out, W1, b1, W2, b2);
    }
}